// Round 5
// baseline (91.751 us; speedup 1.0000x reference)
//
#include <hip/hip_runtime.h>

// PiecewisePolynomial: out[b,o] = sum_i sum_j L_j(x_in(b,i)) * w[o, i, 3*seg(b,i)+j]
// B=512, IN_F=256, OUT_F=256, SEGMENTS=16, N=4 (nodes -1,-0.5,0.5,1)
//
// R5 (= R4 with cvt_pkrtz type fix): f16 weight path. pp_expand converts w to
// f16-pair slot layout we[i][o][32] (8.4 MB in d_ws) matching the LDS tile
// exactly -> pp_partial stages with coalesced 16B global_load_lds, inner loop
// = ds_read_b64 + 2x v_dot2_f32_f16. 32KB LDS -> 4 blocks/CU (16 waves).
// Partials to d_ws, reduced by pp_reduce.

typedef _Float16 h2 __attribute__((ext_vector_type(2)));

#define INF     256
#define OUTF    256
#define WSTRIDE 49
#define OSTRIDE (INF * WSTRIDE)     // 12544
#define NSPLIT  32
#define IPB     8                   // i's per pp_partial block
#define WE_UINTS (256 * 256 * 32)   // 8.4 MB expanded weights (uints)

#define GLOAD16(gptr, lptr)                                                         \
  __builtin_amdgcn_global_load_lds(                                                 \
      (const __attribute__((address_space(1))) unsigned int*)(gptr),                \
      (__attribute__((address_space(3))) unsigned int*)(lptr), 16, 0, 0)

// ---- expand: w[o][i][0..48] f32 -> we[i][o][pair0..31] f16x2 ----
// pair 2s+q = (w[3s+2q], w[3s+2q+1]) : seg s's 4 weights as 2 packed pairs.
__global__ __launch_bounds__(256)
void pp_expand(const float* __restrict__ w, unsigned int* __restrict__ we) {
    const int i = blockIdx.x;        // 0..255
    const int o = threadIdx.x;       // 0..255
    const float* src = w + (size_t)o * OSTRIDE + i * WSTRIDE;
    float t[49];
    #pragma unroll
    for (int k = 0; k < 49; ++k) t[k] = src[k];
    unsigned int pk[32];
    #pragma unroll
    for (int s = 0; s < 16; ++s) {
        auto p0 = __builtin_amdgcn_cvt_pkrtz(t[3*s],   t[3*s+1]);
        auto p1 = __builtin_amdgcn_cvt_pkrtz(t[3*s+2], t[3*s+3]);
        pk[2*s]   = __builtin_bit_cast(unsigned int, p0);
        pk[2*s+1] = __builtin_bit_cast(unsigned int, p1);
    }
    uint4* dst = (uint4*)(we + ((size_t)i * 256 + o) * 32);
    #pragma unroll
    for (int k = 0; k < 8; ++k)
        dst[k] = make_uint4(pk[4*k], pk[4*k+1], pk[4*k+2], pk[4*k+3]);
}

// Stage chunk ci (2 i's, 16 KB): global layout == LDS layout, pure 16B async.
#define STAGE(ci)                                                                   \
do {                                                                                \
    unsigned int* lds_ = &smem[((ci) & 1) * 4096];                                  \
    _Pragma("unroll")                                                               \
    for (int it = 0; it < 4; ++it) {                                                \
        int f_ = it * 256 + tid;              /* 16B units, 0..1023 */              \
        int iloc_ = f_ >> 9;                                                        \
        int rem_  = f_ & 511;                                                       \
        const unsigned int* gp_ = we + ((size_t)(i_base + (ci)*2 + iloc_) * 256     \
                                        + o_base) * 32 + rem_ * 4;                  \
        GLOAD16(gp_, lds_ + f_ * 4);                                                \
    }                                                                               \
} while (0)

// Compute chunk ci: per i, per o: ds_read_b64 at seg slot + 2x v_dot2_f32_f16.
// Lane addrs differ only by seg*8B: same-seg lanes broadcast; s vs s+16 = 2-way.
#define COMPUTE(ci)                                                                 \
do {                                                                                \
    _Pragma("unroll")                                                               \
    for (int il = 0; il < 2; ++il) {                                                \
        const int ig_ = (ci) * 2 + il;                                              \
        const unsigned int* p_ = &smem[((ci) & 1) * 4096                            \
                                       + (il * 64 + o_off) * 32 + sseg[ig_] * 2];   \
        const h2 cA_ = ch01[ig_], cB_ = ch23[ig_];                                  \
        _Pragma("unroll")                                                           \
        for (int oo = 0; oo < 16; ++oo) {                                           \
            uint2 v_ = *(const uint2*)(p_ + oo * 32);                               \
            acc[oo] = __builtin_amdgcn_fdot2(__builtin_bit_cast(h2, v_.x), cA_,     \
                                             acc[oo], false);                       \
            acc[oo] = __builtin_amdgcn_fdot2(__builtin_bit_cast(h2, v_.y), cB_,     \
                                             acc[oo], false);                       \
        }                                                                           \
    }                                                                               \
} while (0)

__global__ __launch_bounds__(256, 4)
void pp_partial(const float* __restrict__ x, const unsigned int* __restrict__ we,
                float* __restrict__ part) {
    __shared__ unsigned int smem[8192];   // 2 bufs x (2i x 64o x 32 pairs) = 32 KB

    const int tid  = threadIdx.x;
    const int wave = tid >> 6, lane = tid & 63;
    const int isplit = blockIdx.x;             // 0..31
    const int i_base = isplit * IPB;
    const int o_base = blockIdx.y * 64;        // 0..3
    const int b_base = blockIdx.z * 64;        // 0..7
    const int b = b_base + lane;               // this lane's batch row
    const int o_off = wave * 16;               // wave's o-quarter within tile

    // ---- per-lane basis + segment for own b at the 8 staged i's ----
    int sseg[IPB];
    h2  ch01[IPB], ch23[IPB];
    {
        const float4* xp = (const float4*)(x + (size_t)b * INF + i_base);
        float4 x0 = xp[0], x1 = xp[1];
        float xs[8] = {x0.x, x0.y, x0.z, x0.w, x1.x, x1.y, x1.z, x1.w};
        #pragma unroll
        for (int i = 0; i < IPB; ++i) {
            float xx = xs[i];
            int id = (int)((xx + 1.0f) * 8.0f);
            id = id < 0 ? 0 : (id > 15 ? 15 : id);
            float u = (xx - ((float)id * 0.125f - 1.0f)) * 16.0f - 1.0f;
            float a = u + 1.0f, b2 = u + 0.5f, cc = u - 0.5f, d = u - 1.0f;
            float c0 = b2 * cc * d  * (-2.0f / 3.0f);
            float c1 = a  * cc * d  * ( 4.0f / 3.0f);
            float c2 = a  * b2 * d  * (-4.0f / 3.0f);
            float c3 = a  * b2 * cc * ( 2.0f / 3.0f);
            h2 pA; pA[0] = (_Float16)c0; pA[1] = (_Float16)c1;
            h2 pB; pB[0] = (_Float16)c2; pB[1] = (_Float16)c3;
            ch01[i] = pA; ch23[i] = pB;
            sseg[i] = id;
        }
    }

    float acc[16];
    #pragma unroll
    for (int q = 0; q < 16; ++q) acc[q] = 0.0f;

    // ---- double-buffered pipeline over 4 chunks of 2 i's ----
    STAGE(0);
    __syncthreads();
    STAGE(1); COMPUTE(0); __syncthreads();
    STAGE(2); COMPUTE(1); __syncthreads();
    STAGE(3); COMPUTE(2); __syncthreads();
    COMPUTE(3);

    // ---- partial: part[isplit][b][o] coalesced float4 stores ----
    float4* wp = (float4*)(part + (size_t)isplit * (512 * 256)
                                + (size_t)b * 256 + o_base + o_off);
    #pragma unroll
    for (int q = 0; q < 4; ++q)
        wp[q] = make_float4(acc[4*q], acc[4*q+1], acc[4*q+2], acc[4*q+3]);
}

__global__ __launch_bounds__(256)
void pp_reduce(const float* __restrict__ part, float* __restrict__ out) {
    const size_t off = (size_t)blockIdx.x * 256 + threadIdx.x;  // b*256 + o
    float s = 0.0f;
    #pragma unroll
    for (int k = 0; k < NSPLIT; ++k)
        s += part[(size_t)k * (512 * 256) + off];
    out[off] = s;
}

extern "C" void kernel_launch(void* const* d_in, const int* in_sizes, int n_in,
                              void* d_out, int out_size, void* d_ws, size_t ws_size,
                              hipStream_t stream) {
    const float* x = (const float*)d_in[0];
    const float* w = (const float*)d_in[1];
    float* out = (float*)d_out;
    unsigned int* we = (unsigned int*)d_ws;                       // 8.4 MB
    float* part = (float*)((char*)d_ws + (size_t)WE_UINTS * 4);   // 16.8 MB
    (void)ws_size; (void)n_in; (void)in_sizes; (void)out_size;

    pp_expand<<<dim3(256), 256, 0, stream>>>(w, we);
    pp_partial<<<dim3(NSPLIT, 4, 8), 256, 0, stream>>>(x, we, part);
    pp_reduce<<<dim3(512), 256, 0, stream>>>(part, out);
}

// Round 6
// 85.194 us; speedup vs baseline: 1.0770x; 1.0770x over previous
//
#include <hip/hip_runtime.h>

// PiecewisePolynomial: out[b,o] = sum_i sum_j L_j(x_in(b,i)) * w[o, i, 3*seg(b,i)+j]
// B=512, IN_F=256, OUT_F=256, SEGMENTS=16, N=4 (nodes -1,-0.5,0.5,1)
//
// R6: single-stage single-barrier pp_partial (kills the per-chunk
// vmcnt(0)+barrier drain that R3/R5 shared). Block = 8i x 32o x 64b,
// 32KB LDS staged once, 4 blocks/CU. o-paired LDS layout: one
// ds_read_b128 = 4 weights x 2 outputs. LDS-transpose epilogue ->
// float4 partial stores; float4 reduce.

typedef _Float16 h2 __attribute__((ext_vector_type(2)));

#define INF     256
#define OUTF    256
#define WSTRIDE 49
#define OSTRIDE (INF * WSTRIDE)       // 12544
#define NSPLIT  32
#define IPB     8
#define WE_UINTS (256 * 128 * 64)     // 2,097,152 uints = 8.39 MB

#define GLOAD16(gptr, lptr)                                                         \
  __builtin_amdgcn_global_load_lds(                                                 \
      (const __attribute__((address_space(1))) unsigned int*)(gptr),                \
      (__attribute__((address_space(3))) unsigned int*)(lptr), 16, 0, 0)

// ---- expand: w[o][i][0..48] f32 -> we[i][op][s] = 16B {o_even pair0, pair1,
//      o_odd pair0, pair1}; pair0 = f16x2(w[3s],w[3s+1]), pair1 = (w[3s+2],w[3s+3])
__global__ __launch_bounds__(256)
void pp_expand(const float* __restrict__ w, unsigned int* __restrict__ we) {
    const int i = blockIdx.x;        // 0..255
    const int o = threadIdx.x;       // 0..255
    const float* src = w + (size_t)o * OSTRIDE + i * WSTRIDE;
    float t[49];
    #pragma unroll
    for (int k = 0; k < 49; ++k) t[k] = src[k];
    const int op = o >> 1, e = o & 1;
    unsigned int* dst = we + ((size_t)i * 128 + op) * 64 + e * 2;
    #pragma unroll
    for (int s = 0; s < 16; ++s) {
        auto p0 = __builtin_amdgcn_cvt_pkrtz(t[3*s],   t[3*s+1]);
        auto p1 = __builtin_amdgcn_cvt_pkrtz(t[3*s+2], t[3*s+3]);
        uint2 v;
        v.x = __builtin_bit_cast(unsigned int, p0);
        v.y = __builtin_bit_cast(unsigned int, p1);
        *(uint2*)(dst + s * 4) = v;
    }
}

__global__ __launch_bounds__(256, 4)
void pp_partial(const float* __restrict__ x, const unsigned int* __restrict__ we,
                float* __restrict__ part) {
    __shared__ unsigned int smem[8192];   // 8i x 16op x 16s x 16B = 32 KB

    const int tid  = threadIdx.x;
    const int wave = tid >> 6, lane = tid & 63;
    const int isplit  = blockIdx.x;            // 0..31
    const int i_base  = isplit * IPB;
    const int op_base = blockIdx.y * 16;       // o_base = blockIdx.y*32
    const int o_base  = blockIdx.y * 32;
    const int b_base  = blockIdx.z * 64;
    const int b = b_base + lane;               // this lane's batch row

    // ---- single stage: whole 32KB slice, 8x 16B per thread, coalesced ----
    #pragma unroll
    for (int it = 0; it < 8; ++it) {
        int u = it * 256 + tid;                // 16B unit 0..2047
        int iloc = u >> 8, opl = (u >> 4) & 15, s = u & 15;
        const unsigned int* gp =
            we + (((size_t)(i_base + iloc) * 128 + op_base + opl) * 16 + s) * 4;
        GLOAD16(gp, &smem[u * 4]);
    }

    // ---- per-lane basis + segment for own b (overlaps with stage in flight) ----
    int sseg[IPB]; h2 cA[IPB], cB[IPB];
    {
        const float4* xp = (const float4*)(x + (size_t)b * INF + i_base);
        float4 x0 = xp[0], x1 = xp[1];
        float xs[8] = {x0.x, x0.y, x0.z, x0.w, x1.x, x1.y, x1.z, x1.w};
        #pragma unroll
        for (int i = 0; i < IPB; ++i) {
            float xx = xs[i];
            int id = (int)((xx + 1.0f) * 8.0f);
            id = id < 0 ? 0 : (id > 15 ? 15 : id);
            float u = (xx - ((float)id * 0.125f - 1.0f)) * 16.0f - 1.0f;
            float a = u + 1.0f, b2 = u + 0.5f, cc = u - 0.5f, d = u - 1.0f;
            float c0 = b2 * cc * d  * (-2.0f / 3.0f);
            float c1 = a  * cc * d  * ( 4.0f / 3.0f);
            float c2 = a  * b2 * d  * (-4.0f / 3.0f);
            float c3 = a  * b2 * cc * ( 2.0f / 3.0f);
            h2 pA; pA[0] = (_Float16)c0; pA[1] = (_Float16)c1;
            h2 pB; pB[0] = (_Float16)c2; pB[1] = (_Float16)c3;
            cA[i] = pA; cB[i] = pB; sseg[i] = id;
        }
    }

    __syncthreads();    // THE one barrier: stage drained, LDS valid

    // ---- uninterrupted compute: 32 ds_read_b128 + 128 fdot2 per wave ----
    // wave covers o = o_base + wave*8 .. +7  (op = wave*4 + pq)
    float acc[8];
    #pragma unroll
    for (int q = 0; q < 8; ++q) acc[q] = 0.0f;

    #pragma unroll
    for (int i = 0; i < IPB; ++i) {
        const unsigned int* p = &smem[(i * 16 + wave * 4) * 64 + sseg[i] * 4];
        #pragma unroll
        for (int pq = 0; pq < 4; ++pq) {
            uint4 v = *(const uint4*)(p + pq * 64);
            acc[2*pq]   = __builtin_amdgcn_fdot2(__builtin_bit_cast(h2, v.x), cA[i],
                                                 acc[2*pq],   false);
            acc[2*pq]   = __builtin_amdgcn_fdot2(__builtin_bit_cast(h2, v.y), cB[i],
                                                 acc[2*pq],   false);
            acc[2*pq+1] = __builtin_amdgcn_fdot2(__builtin_bit_cast(h2, v.z), cA[i],
                                                 acc[2*pq+1], false);
            acc[2*pq+1] = __builtin_amdgcn_fdot2(__builtin_bit_cast(h2, v.w), cB[i],
                                                 acc[2*pq+1], false);
        }
    }

    // ---- LDS transpose (lane=b -> lane=o) + coalesced float4 partial stores ----
    __syncthreads();                      // weights no longer needed
    float* smf = (float*)smem;            // [64 b][33] fp32 = 8448 B
    #pragma unroll
    for (int q = 0; q < 8; ++q)
        smf[lane * 33 + wave * 8 + q] = acc[q];
    __syncthreads();

    const int qo = tid & 7;               // o-quad 0..7 (4 floats each)
    const int g  = tid >> 3;              // 0..31
    #pragma unroll
    for (int r = 0; r < 2; ++r) {
        int b_l = g + 32 * r;
        float4 v;
        v.x = smf[b_l * 33 + qo * 4 + 0];
        v.y = smf[b_l * 33 + qo * 4 + 1];
        v.z = smf[b_l * 33 + qo * 4 + 2];
        v.w = smf[b_l * 33 + qo * 4 + 3];
        *(float4*)(part + (size_t)isplit * (512 * 256)
                        + (size_t)(b_base + b_l) * 256 + o_base + qo * 4) = v;
    }
}

__global__ __launch_bounds__(256)
void pp_reduce(const float* __restrict__ part, float* __restrict__ out) {
    const size_t off4 = (size_t)blockIdx.x * 256 + threadIdx.x;  // float4 index
    const float4* p4 = (const float4*)part;
    float4 s = make_float4(0.f, 0.f, 0.f, 0.f);
    #pragma unroll
    for (int k = 0; k < NSPLIT; ++k) {
        float4 v = p4[(size_t)k * (512 * 64) + off4];
        s.x += v.x; s.y += v.y; s.z += v.z; s.w += v.w;
    }
    ((float4*)out)[off4] = s;
}

extern "C" void kernel_launch(void* const* d_in, const int* in_sizes, int n_in,
                              void* d_out, int out_size, void* d_ws, size_t ws_size,
                              hipStream_t stream) {
    const float* x = (const float*)d_in[0];
    const float* w = (const float*)d_in[1];
    float* out = (float*)d_out;
    unsigned int* we = (unsigned int*)d_ws;                       // 8.39 MB
    float* part = (float*)((char*)d_ws + (size_t)WE_UINTS * 4);   // 16.8 MB
    (void)ws_size; (void)n_in; (void)in_sizes; (void)out_size;

    pp_expand<<<dim3(256), 256, 0, stream>>>(w, we);
    pp_partial<<<dim3(NSPLIT, 8, 8), 256, 0, stream>>>(x, we, part);
    pp_reduce<<<dim3(128), 256, 0, stream>>>(part, out);   // 128*256 float4 = 131072 floats
}